// Round 3
// baseline (167.096 us; speedup 1.0000x reference)
//
#include <hip/hip_runtime.h>

#define NB 1024
#define ND 256
#define APB 4             // anchors per block
#define NBLK (NB/APB)     // 256 blocks
#define NTHR 1024         // 16 waves
#define NWAVE 16
#define MARGINF 0.3f
#define BIGV 1e9f
#define D2R 0.017453292519943295f
#define HD2R 0.008726646259971648f   // 0.5 * D2R

// haversine 'a' thresholds: sin^2(T / (2*6371000)), double precision offline
#define A_POS 3.8495040e-12f   // 25 m
#define A_NEG 6.1592064e-11f   // 100 m

__device__ __forceinline__ float d4(float4 a, float4 b, float acc) {
    return fmaf(a.x,b.x, fmaf(a.y,b.y, fmaf(a.z,b.z, fmaf(a.w,b.w, acc))));
}
__device__ __forceinline__ float sel4(int s, float x0, float x1, float x2, float x3) {
    float r = (s == 0) ? x0 : x1;
    r = (s == 2) ? x2 : r;
    r = (s == 3) ? x3 : r;
    return r;
}

__global__ __launch_bounds__(NTHR, 4) void triplet_main(
    const float* __restrict__ emb, const float* __restrict__ gps,
    float* __restrict__ tri, float* __restrict__ val)
{
    __shared__ float4 sA4[APB][ND/4];   // 4 KB anchor rows
    __shared__ float2 sGPS[NB];         // 8 KB lat/lon (degrees)
    __shared__ float  sCJ[NB];          // 4 KB cos(lat)
    __shared__ float  wmax[NWAVE][APB], wmin[NWAVE][APB], wsmin[NWAVE][APB];
    __shared__ float  sdap[APB], sneg[APB];

    const int tid  = threadIdx.x;
    const int lane = tid & 63;
    const int wave = tid >> 6;
    const int jj   = lane >> 4;     // row within quartet
    const int kk   = lane & 15;     // k-slice
    const int am   = kk & 3;        // anchor this lane owns for scalar work
    const int i0   = blockIdx.x * APB;

    // coalesced staging
    if (tid < APB*(ND/4))
        ((float4*)sA4)[tid] = ((const float4*)emb)[i0*(ND/4) + tid];
    {
        float2 g = ((const float2*)gps)[tid];
        sGPS[tid] = g;
        sCJ[tid]  = cosf(g.x * D2R);
    }
    __syncthreads();

    // anchor k-slices into registers: 16 float4 = 64 VGPR, reused 16x
    float4 cA[APB][4];
    #pragma unroll
    for (int a = 0; a < APB; ++a)
        #pragma unroll
        for (int c = 0; c < 4; ++c)
            cA[a][c] = sA4[a][kk + 16*c];

    // anchor squared norms (k-split + group reduce), keep own anchor's
    float SAall[APB];
    #pragma unroll
    for (int a = 0; a < APB; ++a) {
        float s = 0.f;
        #pragma unroll
        for (int c = 0; c < 4; ++c) s = d4(cA[a][c], cA[a][c], s);
        #pragma unroll
        for (int off = 1; off < 16; off <<= 1) s += __shfl_xor(s, off);
        SAall[a] = s;
    }
    const float SA = sel4(am, SAall[0], SAall[1], SAall[2], SAall[3]);

    const float2 gA = sGPS[i0 + am];
    const float latA = gA.x, lonA = gA.y;
    const float cosA = sCJ[i0 + am];

    float pmax = -1.f, nmin = BIGV;
    unsigned negbits = 0;
    float dsv[16];

    #pragma unroll
    for (int t = 0; t < 16; ++t) {
        const int j = (wave << 6) + (t << 2) + jj;
        const float4* __restrict__ row = (const float4*)(emb + (size_t)j * ND);
        // fully coalesced: 64 lanes cover 4 rows x 256 contiguous bytes
        float4 v0 = row[kk], v1 = row[kk+16], v2 = row[kk+32], v3 = row[kk+48];
        float sq = d4(v3, v3, d4(v2, v2, d4(v1, v1, d4(v0, v0, 0.f))));
        float ac[APB];
        #pragma unroll
        for (int a = 0; a < APB; ++a)
            ac[a] = d4(v3, cA[a][3], d4(v2, cA[a][2], d4(v1, cA[a][1], d4(v0, cA[a][0], 0.f))));
        // reduce over the 16-lane k-group
        #pragma unroll
        for (int off = 1; off < 16; off <<= 1) {
            sq += __shfl_xor(sq, off);
            #pragma unroll
            for (int a = 0; a < APB; ++a) ac[a] += __shfl_xor(ac[a], off);
        }
        const float acm = sel4(am, ac[0], ac[1], ac[2], ac[3]);
        const float d2 = SA + sq - 2.f*acm;
        const float d  = d2 > 0.f ? sqrtf(d2) : 0.f;
        const float2 gj = sGPS[j];
        const float cj  = sCJ[j];
        const float sla = sinf((gj.x - latA) * HD2R);
        const float slo = sinf((gj.y - lonA) * HD2R);
        const float hav = fmaf(sla, sla, (cosA*cj) * (slo*slo));
        const bool pos = (hav < A_POS) && (j != i0 + am);
        const bool neg = (hav > A_NEG);
        pmax = fmaxf(pmax, pos ? d : -1.f);
        nmin = fminf(nmin, neg ? d : BIGV);
        negbits |= (neg ? 1u : 0u) << t;
        dsv[t] = d;
    }

    // reduce across lanes sharing the same anchor (bits 2..5)
    #pragma unroll
    for (int off = 4; off < 64; off <<= 1) {
        pmax = fmaxf(pmax, __shfl_xor(pmax, off));
        nmin = fminf(nmin, __shfl_xor(nmin, off));
    }
    if (lane < APB) { wmax[wave][lane] = pmax; wmin[wave][lane] = nmin; }
    __syncthreads();

    if (wave == 0) {
        float vmax = wmax[lane >> 2][lane & 3];
        float vmin = wmin[lane >> 2][lane & 3];
        #pragma unroll
        for (int off = 4; off < 64; off <<= 1) {
            vmax = fmaxf(vmax, __shfl_xor(vmax, off));
            vmin = fminf(vmin, __shfl_xor(vmin, off));
        }
        if (lane < APB) { sdap[lane] = vmax; sneg[lane] = vmin; }
    }
    __syncthreads();

    // semi-hard pass in registers
    const float dap = sdap[am];
    float smin = BIGV;
    #pragma unroll
    for (int t = 0; t < 16; ++t) {
        float d = dsv[t];
        bool ok = ((negbits >> t) & 1u) && (d > dap) && (d < dap + MARGINF);
        smin = fminf(smin, ok ? d : BIGV);
    }
    #pragma unroll
    for (int off = 4; off < 64; off <<= 1)
        smin = fminf(smin, __shfl_xor(smin, off));
    if (lane < APB) wsmin[wave][lane] = smin;
    __syncthreads();

    if (wave == 0) {
        float vs = wsmin[lane >> 2][lane & 3];
        #pragma unroll
        for (int off = 4; off < 64; off <<= 1) vs = fminf(vs, __shfl_xor(vs, off));
        if (lane < APB) {
            const int a = lane;
            const float dapf   = sdap[a];
            const float negmin = sneg[a];
            bool has_pos  = dapf > -0.5f;
            bool has_neg  = negmin < 0.5f*BIGV;
            bool has_semi = vs < 0.5f*BIGV;
            float dan = has_semi ? vs : negmin;
            bool valid = has_pos && has_neg;
            float t = dapf - dan + MARGINF;
            t = t > 0.f ? t : 0.f;
            tri[i0+a] = valid ? t : 0.f;
            val[i0+a] = valid ? 1.f : 0.f;
        }
    }
}

__global__ __launch_bounds__(256) void triplet_final(
    const float* __restrict__ tri, const float* __restrict__ val, float* __restrict__ out)
{
    const int tid = threadIdx.x;
    float st = 0.f, sv = 0.f;
    #pragma unroll
    for (int g = 0; g < 4; ++g) { st += tri[tid + (g<<8)]; sv += val[tid + (g<<8)]; }
    #pragma unroll
    for (int off = 32; off; off >>= 1) { st += __shfl_xor(st, off); sv += __shfl_xor(sv, off); }
    __shared__ float rt[4], rv[4];
    if ((tid & 63) == 0) { rt[tid>>6] = st; rv[tid>>6] = sv; }
    __syncthreads();
    if (tid == 0) {
        float t = rt[0]+rt[1]+rt[2]+rt[3];
        float v = rv[0]+rv[1]+rv[2]+rv[3];
        out[0] = t / fmaxf(v, 1.f);
    }
}

extern "C" void kernel_launch(void* const* d_in, const int* in_sizes, int n_in,
                              void* d_out, int out_size, void* d_ws, size_t ws_size,
                              hipStream_t stream) {
    const float* emb = (const float*)d_in[0];   // [1024,256] f32
    const float* gps = (const float*)d_in[1];   // [1024,2]  f32
    float* tri = (float*)d_ws;                  // [1024]
    float* val = tri + NB;                      // [1024]
    triplet_main<<<NBLK, NTHR, 0, stream>>>(emb, gps, tri, val);
    triplet_final<<<1, 256, 0, stream>>>(tri, val, (float*)d_out);
}

// Round 4
// 48.132 us; speedup vs baseline: 3.4716x; 3.4716x over previous
//
#include <hip/hip_runtime.h>

#define NB 1024
#define ND 256
#define APB 4             // anchors per block
#define NBLK (NB/APB)     // 256 blocks
#define NTHR 1024         // 16 waves, 1 block/CU
#define NWAVE 16
#define MARGINF 0.3f
#define BIGV 1e9f
#define D2R 0.017453292519943295f
#define HD2R 0.008726646259971648f   // 0.5 * D2R

// haversine 'a' thresholds: sin^2(T / (2*6371000)), double precision offline
#define A_POS 3.8495040e-12f   // 25 m
#define A_NEG 6.1592064e-11f   // 100 m

__device__ __forceinline__ float d4(float4 a, float4 b, float acc) {
    return fmaf(a.x,b.x, fmaf(a.y,b.y, fmaf(a.z,b.z, fmaf(a.w,b.w, acc))));
}
__device__ __forceinline__ float sel4(int s, float x0, float x1, float x2, float x3) {
    float r = (s == 0) ? x0 : x1;
    r = (s == 2) ? x2 : r;
    r = (s == 3) ? x3 : r;
    return r;
}

__global__ __launch_bounds__(NTHR)
__attribute__((amdgpu_waves_per_eu(4, 4)))   // pin 4 waves/EU -> 128-VGPR budget, no spill
void triplet_main(
    const float* __restrict__ emb, const float* __restrict__ gps,
    float* __restrict__ tri, float* __restrict__ val)
{
    __shared__ float4 sA4[APB][ND/4];        // 4 KB anchor rows
    __shared__ float2 sGPS[NB];              // 8 KB lat/lon (degrees)
    __shared__ float  sCJ[NB];               // 4 KB cos(lat)
    __shared__ float  sDSV[16][NTHR];        // 64 KB: per-thread distances (was VGPR -> spill)
    __shared__ float  wmax[NWAVE][APB], wmin[NWAVE][APB], wsmin[NWAVE][APB];
    __shared__ float  sdap[APB], sneg[APB];

    const int tid  = threadIdx.x;
    const int lane = tid & 63;
    const int wave = tid >> 6;
    const int jj   = lane >> 4;     // row within quartet
    const int kk   = lane & 15;     // k-slice
    const int am   = kk & 3;        // anchor this lane owns for scalar work
    const int i0   = blockIdx.x * APB;

    // coalesced staging
    if (tid < APB*(ND/4))
        ((float4*)sA4)[tid] = ((const float4*)emb)[i0*(ND/4) + tid];
    {
        float2 g = ((const float2*)gps)[tid];
        sGPS[tid] = g;
        sCJ[tid]  = cosf(g.x * D2R);
    }
    __syncthreads();

    // anchor k-slices into registers: 16 float4 = 64 VGPR, reused 16x
    float4 cA[APB][4];
    #pragma unroll
    for (int a = 0; a < APB; ++a)
        #pragma unroll
        for (int c = 0; c < 4; ++c)
            cA[a][c] = sA4[a][kk + 16*c];

    // anchor squared norms (k-split + group reduce), keep own anchor's
    float SAall[APB];
    #pragma unroll
    for (int a = 0; a < APB; ++a) {
        float s = 0.f;
        #pragma unroll
        for (int c = 0; c < 4; ++c) s = d4(cA[a][c], cA[a][c], s);
        #pragma unroll
        for (int off = 1; off < 16; off <<= 1) s += __shfl_xor(s, off);
        SAall[a] = s;
    }
    const float SA = sel4(am, SAall[0], SAall[1], SAall[2], SAall[3]);

    const float2 gA = sGPS[i0 + am];
    const float latA = gA.x, lonA = gA.y;
    const float cosA = sCJ[i0 + am];

    float pmax = -1.f, nmin = BIGV;
    unsigned negbits = 0;

    #pragma unroll 4
    for (int t = 0; t < 16; ++t) {
        const int j = (wave << 6) + (t << 2) + jj;
        const float4* __restrict__ row = (const float4*)(emb + (size_t)j * ND);
        // fully coalesced: 64 lanes cover 4 rows x 256 contiguous bytes
        float4 v0 = row[kk], v1 = row[kk+16], v2 = row[kk+32], v3 = row[kk+48];
        float sq = d4(v3, v3, d4(v2, v2, d4(v1, v1, d4(v0, v0, 0.f))));
        float ac[APB];
        #pragma unroll
        for (int a = 0; a < APB; ++a)
            ac[a] = d4(v3, cA[a][3], d4(v2, cA[a][2], d4(v1, cA[a][1], d4(v0, cA[a][0], 0.f))));
        // reduce over the 16-lane k-group
        #pragma unroll
        for (int off = 1; off < 16; off <<= 1) {
            sq += __shfl_xor(sq, off);
            #pragma unroll
            for (int a = 0; a < APB; ++a) ac[a] += __shfl_xor(ac[a], off);
        }
        const float acm = sel4(am, ac[0], ac[1], ac[2], ac[3]);
        const float d2 = SA + sq - 2.f*acm;
        const float d  = d2 > 0.f ? sqrtf(d2) : 0.f;
        const float2 gj = sGPS[j];
        const float cj  = sCJ[j];
        const float sla = sinf((gj.x - latA) * HD2R);
        const float slo = sinf((gj.y - lonA) * HD2R);
        const float hav = fmaf(sla, sla, (cosA*cj) * (slo*slo));
        const bool pos = (hav < A_POS) && (j != i0 + am);
        const bool neg = (hav > A_NEG);
        pmax = fmaxf(pmax, pos ? d : -1.f);
        nmin = fminf(nmin, neg ? d : BIGV);
        negbits |= (neg ? 1u : 0u) << t;
        sDSV[t][tid] = d;
    }

    // reduce across lanes sharing the same anchor (bits 2..5 of lane)
    #pragma unroll
    for (int off = 4; off < 64; off <<= 1) {
        pmax = fmaxf(pmax, __shfl_xor(pmax, off));
        nmin = fminf(nmin, __shfl_xor(nmin, off));
    }
    if (lane < APB) { wmax[wave][lane] = pmax; wmin[wave][lane] = nmin; }
    __syncthreads();

    if (wave == 0) {
        float vmax = wmax[lane >> 2][lane & 3];
        float vmin = wmin[lane >> 2][lane & 3];
        #pragma unroll
        for (int off = 4; off < 64; off <<= 1) {
            vmax = fmaxf(vmax, __shfl_xor(vmax, off));
            vmin = fminf(vmin, __shfl_xor(vmin, off));
        }
        if (lane < APB) { sdap[lane] = vmax; sneg[lane] = vmin; }
    }
    __syncthreads();

    // semi-hard pass: distances from LDS, window vs dap
    const float dap = sdap[am];
    float smin = BIGV;
    #pragma unroll 4
    for (int t = 0; t < 16; ++t) {
        float d = sDSV[t][tid];
        bool ok = ((negbits >> t) & 1u) && (d > dap) && (d < dap + MARGINF);
        smin = fminf(smin, ok ? d : BIGV);
    }
    #pragma unroll
    for (int off = 4; off < 64; off <<= 1)
        smin = fminf(smin, __shfl_xor(smin, off));
    if (lane < APB) wsmin[wave][lane] = smin;
    __syncthreads();

    if (wave == 0) {
        float vs = wsmin[lane >> 2][lane & 3];
        #pragma unroll
        for (int off = 4; off < 64; off <<= 1) vs = fminf(vs, __shfl_xor(vs, off));
        if (lane < APB) {
            const int a = lane;
            const float dapf   = sdap[a];
            const float negmin = sneg[a];
            bool has_pos  = dapf > -0.5f;
            bool has_neg  = negmin < 0.5f*BIGV;
            bool has_semi = vs < 0.5f*BIGV;
            float dan = has_semi ? vs : negmin;
            bool valid = has_pos && has_neg;
            float t = dapf - dan + MARGINF;
            t = t > 0.f ? t : 0.f;
            tri[i0+a] = valid ? t : 0.f;
            val[i0+a] = valid ? 1.f : 0.f;
        }
    }
}

__global__ __launch_bounds__(256) void triplet_final(
    const float* __restrict__ tri, const float* __restrict__ val, float* __restrict__ out)
{
    const int tid = threadIdx.x;
    float st = 0.f, sv = 0.f;
    #pragma unroll
    for (int g = 0; g < 4; ++g) { st += tri[tid + (g<<8)]; sv += val[tid + (g<<8)]; }
    #pragma unroll
    for (int off = 32; off; off >>= 1) { st += __shfl_xor(st, off); sv += __shfl_xor(sv, off); }
    __shared__ float rt[4], rv[4];
    if ((tid & 63) == 0) { rt[tid>>6] = st; rv[tid>>6] = sv; }
    __syncthreads();
    if (tid == 0) {
        float t = rt[0]+rt[1]+rt[2]+rt[3];
        float v = rv[0]+rv[1]+rv[2]+rv[3];
        out[0] = t / fmaxf(v, 1.f);
    }
}

extern "C" void kernel_launch(void* const* d_in, const int* in_sizes, int n_in,
                              void* d_out, int out_size, void* d_ws, size_t ws_size,
                              hipStream_t stream) {
    const float* emb = (const float*)d_in[0];   // [1024,256] f32
    const float* gps = (const float*)d_in[1];   // [1024,2]  f32
    float* tri = (float*)d_ws;                  // [1024]
    float* val = tri + NB;                      // [1024]
    triplet_main<<<NBLK, NTHR, 0, stream>>>(emb, gps, tri, val);
    triplet_final<<<1, 256, 0, stream>>>(tri, val, (float*)d_out);
}